// Round 1
// baseline (4890.106 us; speedup 1.0000x reference)
//
#include <hip/hip_runtime.h>
#include <hip/hip_bf16.h>

// Problem dims (fixed by the reference)
#define T_DIM 8192
#define D_DIM 4096
#define H_DIM 11008

typedef __attribute__((ext_vector_type(8))) __bf16 bf16x8;
typedef __attribute__((ext_vector_type(4))) float f32x4;

typedef __attribute__((address_space(1))) const void gvoid_t;
typedef __attribute__((address_space(3))) void lvoid_t;

__device__ __forceinline__ void async_lds16(const void* g, void* l) {
    // 16B per lane, LDS dest = wave-uniform base + lane*16
    __builtin_amdgcn_global_load_lds((gvoid_t*)g, (lvoid_t*)l, 16, 0, 0);
}

__device__ const float NF4_TAB[16] = {
    -1.0f, -0.6961928009986877f, -0.5250730514526367f, -0.39491748809814453f,
    -0.28444138169288635f, -0.18477343022823334f, -0.09105003625154495f, 0.0f,
    0.07958029955625534f, 0.16093020141124725f, 0.24611230194568634f,
    0.33791524171829224f, 0.44070982933044434f, 0.5626170039176941f,
    0.7229568362236023f, 1.0f};

// ---------------- dequant: int32 codes + per-64 scalers -> bf16 ----------------
__global__ void dequant_nf4_kernel(const int* __restrict__ codes,
                                   const float* __restrict__ scalers,
                                   __bf16* __restrict__ out, long n) {
    __shared__ float tbl[16];
    if (threadIdx.x < 16) tbl[threadIdx.x] = NF4_TAB[threadIdx.x];
    __syncthreads();
    long i = ((long)blockIdx.x * blockDim.x + threadIdx.x) * 8;
    if (i >= n) return;
    float s = scalers[i >> 6];
    const int4* cp = (const int4*)(codes + i);
    int4 c0 = cp[0], c1 = cp[1];
    bf16x8 v;
    v[0] = (__bf16)(tbl[c0.x] * s);
    v[1] = (__bf16)(tbl[c0.y] * s);
    v[2] = (__bf16)(tbl[c0.z] * s);
    v[3] = (__bf16)(tbl[c0.w] * s);
    v[4] = (__bf16)(tbl[c1.x] * s);
    v[5] = (__bf16)(tbl[c1.y] * s);
    v[6] = (__bf16)(tbl[c1.z] * s);
    v[7] = (__bf16)(tbl[c1.w] * s);
    *(bf16x8*)(out + i) = v;
}

// ---------------- x: fp32 -> bf16 ----------------
__global__ void cvt_f32_bf16(const float* __restrict__ x, __bf16* __restrict__ out, long n) {
    long i = ((long)blockIdx.x * blockDim.x + threadIdx.x) * 8;
    if (i >= n) return;
    const float4* xp = (const float4*)(x + i);
    float4 f0 = xp[0], f1 = xp[1];
    bf16x8 v;
    v[0] = (__bf16)f0.x; v[1] = (__bf16)f0.y; v[2] = (__bf16)f0.z; v[3] = (__bf16)f0.w;
    v[4] = (__bf16)f1.x; v[5] = (__bf16)f1.y; v[6] = (__bf16)f1.z; v[7] = (__bf16)f1.w;
    *(bf16x8*)(out + i) = v;
}

// ---------------- GEMM1 fused: h = silu(x@w1^T) * (x@w2^T), bf16 out ----------------
// NT layout: X [T,D] K-major, W [H,D] K-major. 128x128 tile, BK=32, 4 waves (2x2),
// each wave 64x64 as 4x4 of 16x16x32 MFMA tiles. m97 structure.
__global__ __launch_bounds__(256) void gemm1_fused(
    const __bf16* __restrict__ X, const __bf16* __restrict__ W1,
    const __bf16* __restrict__ W2, __bf16* __restrict__ Hb)
{
    __shared__ __bf16 As [128 * 32];
    __shared__ __bf16 B1s[128 * 32];
    __shared__ __bf16 B2s[128 * 32];

    const int tid  = threadIdx.x;
    const int lane = tid & 63;
    const int wave = tid >> 6;
    const int wm = wave >> 1, wn = wave & 1;
    const long m0 = (long)blockIdx.y * 128;
    const long n0 = (long)blockIdx.x * 128;

    // staging: wave w covers rows w*16..w*16+15 (pass p adds 64); lane l -> row +l/4, col (l%4)*8
    const int  srow = wave * 16 + (lane >> 2);
    const int  scol = (lane & 3) * 8;
    const __bf16* Ag  = X  + (m0 + srow) * D_DIM + scol;
    const __bf16* B1g = W1 + (n0 + srow) * D_DIM + scol;
    const __bf16* B2g = W2 + (n0 + srow) * D_DIM + scol;
    const int lds_base = wave * 16 * 32;  // elements; wave-uniform

    // compute-side fragment offsets (elements): row-major [128][32]
    const int ar = (wm * 64 + (lane & 15)) * 32 + (lane >> 4) * 8;
    const int br = (wn * 64 + (lane & 15)) * 32 + (lane >> 4) * 8;

    const f32x4 zero = {0.f, 0.f, 0.f, 0.f};
    f32x4 acc1[4][4], acc2[4][4];
#pragma unroll
    for (int i = 0; i < 4; ++i)
#pragma unroll
        for (int j = 0; j < 4; ++j) { acc1[i][j] = zero; acc2[i][j] = zero; }

    for (int k0 = 0; k0 < D_DIM; k0 += 32) {
#pragma unroll
        for (int p = 0; p < 2; ++p) {
            async_lds16(Ag  + (long)p * 64 * D_DIM + k0, &As [lds_base + p * 64 * 32]);
            async_lds16(B1g + (long)p * 64 * D_DIM + k0, &B1s[lds_base + p * 64 * 32]);
            async_lds16(B2g + (long)p * 64 * D_DIM + k0, &B2s[lds_base + p * 64 * 32]);
        }
        __syncthreads();
        bf16x8 af[4], b1f[4], b2f[4];
#pragma unroll
        for (int i = 0; i < 4; ++i) {
            af[i]  = *(const bf16x8*)(As  + ar + i * 16 * 32);
            b1f[i] = *(const bf16x8*)(B1s + br + i * 16 * 32);
            b2f[i] = *(const bf16x8*)(B2s + br + i * 16 * 32);
        }
#pragma unroll
        for (int mi = 0; mi < 4; ++mi)
#pragma unroll
            for (int ni = 0; ni < 4; ++ni) {
                acc1[mi][ni] = __builtin_amdgcn_mfma_f32_16x16x32_bf16(af[mi], b1f[ni], acc1[mi][ni], 0, 0, 0);
                acc2[mi][ni] = __builtin_amdgcn_mfma_f32_16x16x32_bf16(af[mi], b2f[ni], acc2[mi][ni], 0, 0, 0);
            }
        __syncthreads();
    }

    // epilogue: C/D layout col=lane&15, row=(lane>>4)*4+reg
    const long crow = m0 + wm * 64 + ((lane >> 4) * 4);
    const long ccol = n0 + wn * 64 + (lane & 15);
#pragma unroll
    for (int mi = 0; mi < 4; ++mi)
#pragma unroll
        for (int ni = 0; ni < 4; ++ni)
#pragma unroll
            for (int r = 0; r < 4; ++r) {
                float a = acc1[mi][ni][r];
                float b = acc2[mi][ni][r];
                float sg = 1.0f / (1.0f + __expf(-a));
                float h = a * sg * b;
                Hb[(crow + mi * 16 + r) * H_DIM + (ccol + ni * 16)] = (__bf16)h;
            }
}

// ---------------- GEMM2: out = h @ w3^T, fp32 out ----------------
// h [T,H] K-major, w3 [D,H] K-major. K = 11008 = 344*32.
__global__ __launch_bounds__(256) void gemm2_kernel(
    const __bf16* __restrict__ Hm, const __bf16* __restrict__ W3,
    float* __restrict__ Out)
{
    __shared__ __bf16 As[128 * 32];
    __shared__ __bf16 Bs[128 * 32];

    const int tid  = threadIdx.x;
    const int lane = tid & 63;
    const int wave = tid >> 6;
    const int wm = wave >> 1, wn = wave & 1;
    const long m0 = (long)blockIdx.y * 128;
    const long n0 = (long)blockIdx.x * 128;

    const int  srow = wave * 16 + (lane >> 2);
    const int  scol = (lane & 3) * 8;
    const __bf16* Ag = Hm + (m0 + srow) * (long)H_DIM + scol;
    const __bf16* Bg = W3 + (n0 + srow) * (long)H_DIM + scol;
    const int lds_base = wave * 16 * 32;

    const int ar = (wm * 64 + (lane & 15)) * 32 + (lane >> 4) * 8;
    const int br = (wn * 64 + (lane & 15)) * 32 + (lane >> 4) * 8;

    const f32x4 zero = {0.f, 0.f, 0.f, 0.f};
    f32x4 acc[4][4];
#pragma unroll
    for (int i = 0; i < 4; ++i)
#pragma unroll
        for (int j = 0; j < 4; ++j) acc[i][j] = zero;

    for (int k0 = 0; k0 < H_DIM; k0 += 32) {
#pragma unroll
        for (int p = 0; p < 2; ++p) {
            async_lds16(Ag + (long)p * 64 * H_DIM + k0, &As[lds_base + p * 64 * 32]);
            async_lds16(Bg + (long)p * 64 * H_DIM + k0, &Bs[lds_base + p * 64 * 32]);
        }
        __syncthreads();
        bf16x8 af[4], bf[4];
#pragma unroll
        for (int i = 0; i < 4; ++i) {
            af[i] = *(const bf16x8*)(As + ar + i * 16 * 32);
            bf[i] = *(const bf16x8*)(Bs + br + i * 16 * 32);
        }
#pragma unroll
        for (int mi = 0; mi < 4; ++mi)
#pragma unroll
            for (int ni = 0; ni < 4; ++ni)
                acc[mi][ni] = __builtin_amdgcn_mfma_f32_16x16x32_bf16(af[mi], bf[ni], acc[mi][ni], 0, 0, 0);
        __syncthreads();
    }

    const long crow = m0 + wm * 64 + ((lane >> 4) * 4);
    const long ccol = n0 + wn * 64 + (lane & 15);
#pragma unroll
    for (int mi = 0; mi < 4; ++mi)
#pragma unroll
        for (int ni = 0; ni < 4; ++ni)
#pragma unroll
            for (int r = 0; r < 4; ++r)
                Out[(crow + mi * 16 + r) * D_DIM + (ccol + ni * 16)] = acc[mi][ni][r];
}

extern "C" void kernel_launch(void* const* d_in, const int* in_sizes, int n_in,
                              void* d_out, int out_size, void* d_ws, size_t ws_size,
                              hipStream_t stream) {
    const float* x   = (const float*)d_in[0];
    const int*   w1c = (const int*)d_in[1];
    const float* w1s = (const float*)d_in[2];
    const int*   w2c = (const int*)d_in[3];
    const float* w2s = (const float*)d_in[4];
    const int*   w3c = (const int*)d_in[5];
    const float* w3s = (const float*)d_in[6];
    float* out = (float*)d_out;

    // workspace layout (total ~494 MiB)
    char* ws = (char*)d_ws;
    __bf16* xb  = (__bf16*)ws;  ws += (size_t)T_DIM * D_DIM * 2;
    __bf16* w1b = (__bf16*)ws;  ws += (size_t)H_DIM * D_DIM * 2;
    __bf16* w2b = (__bf16*)ws;  ws += (size_t)H_DIM * D_DIM * 2;
    __bf16* w3b = (__bf16*)ws;  ws += (size_t)H_DIM * D_DIM * 2;
    __bf16* hb  = (__bf16*)ws;  // T*H bf16

    const long nx = (long)T_DIM * D_DIM;   // 33,554,432
    const long nw = (long)H_DIM * D_DIM;   // 45,088,768

    cvt_f32_bf16<<<(int)(nx / (256 * 8)), 256, 0, stream>>>(x, xb, nx);
    dequant_nf4_kernel<<<(int)(nw / (256 * 8)), 256, 0, stream>>>(w1c, w1s, w1b, nw);
    dequant_nf4_kernel<<<(int)(nw / (256 * 8)), 256, 0, stream>>>(w2c, w2s, w2b, nw);
    dequant_nf4_kernel<<<(int)(nw / (256 * 8)), 256, 0, stream>>>(w3c, w3s, w3b, nw);

    gemm1_fused<<<dim3(H_DIM / 128, T_DIM / 128), 256, 0, stream>>>(xb, w1b, w2b, hb);
    gemm2_kernel<<<dim3(D_DIM / 128, T_DIM / 128), 256, 0, stream>>>(hb, w3b, out);
}

// Round 2
// 3984.875 us; speedup vs baseline: 1.2272x; 1.2272x over previous
//
#include <hip/hip_runtime.h>
#include <hip/hip_bf16.h>

// Problem dims (fixed by the reference)
#define T_DIM 8192
#define D_DIM 4096
#define H_DIM 11008

typedef __attribute__((ext_vector_type(8))) __bf16 bf16x8;
typedef __attribute__((ext_vector_type(4))) float f32x4;

typedef __attribute__((address_space(1))) const void gvoid_t;
typedef __attribute__((address_space(3))) void lvoid_t;

__device__ __forceinline__ void async_lds16(const void* g, void* l) {
    // 16B per lane, LDS dest = wave-uniform base + lane*16
    __builtin_amdgcn_global_load_lds((gvoid_t*)g, (lvoid_t*)l, 16, 0, 0);
}

__device__ const float NF4_TAB[16] = {
    -1.0f, -0.6961928009986877f, -0.5250730514526367f, -0.39491748809814453f,
    -0.28444138169288635f, -0.18477343022823334f, -0.09105003625154495f, 0.0f,
    0.07958029955625534f, 0.16093020141124725f, 0.24611230194568634f,
    0.33791524171829224f, 0.44070982933044434f, 0.5626170039176941f,
    0.7229568362236023f, 1.0f};

// ---------------- dequant: int32 codes + per-64 scalers -> bf16 ----------------
__global__ void dequant_nf4_kernel(const int* __restrict__ codes,
                                   const float* __restrict__ scalers,
                                   __bf16* __restrict__ out, long n) {
    __shared__ float tbl[16];
    if (threadIdx.x < 16) tbl[threadIdx.x] = NF4_TAB[threadIdx.x];
    __syncthreads();
    long i = ((long)blockIdx.x * blockDim.x + threadIdx.x) * 8;
    if (i >= n) return;
    float s = scalers[i >> 6];
    const int4* cp = (const int4*)(codes + i);
    int4 c0 = cp[0], c1 = cp[1];
    bf16x8 v;
    v[0] = (__bf16)(tbl[c0.x] * s);
    v[1] = (__bf16)(tbl[c0.y] * s);
    v[2] = (__bf16)(tbl[c0.z] * s);
    v[3] = (__bf16)(tbl[c0.w] * s);
    v[4] = (__bf16)(tbl[c1.x] * s);
    v[5] = (__bf16)(tbl[c1.y] * s);
    v[6] = (__bf16)(tbl[c1.z] * s);
    v[7] = (__bf16)(tbl[c1.w] * s);
    *(bf16x8*)(out + i) = v;
}

// ---------------- x: fp32 -> bf16 ----------------
__global__ void cvt_f32_bf16(const float* __restrict__ x, __bf16* __restrict__ out, long n) {
    long i = ((long)blockIdx.x * blockDim.x + threadIdx.x) * 8;
    if (i >= n) return;
    const float4* xp = (const float4*)(x + i);
    float4 f0 = xp[0], f1 = xp[1];
    bf16x8 v;
    v[0] = (__bf16)f0.x; v[1] = (__bf16)f0.y; v[2] = (__bf16)f0.z; v[3] = (__bf16)f0.w;
    v[4] = (__bf16)f1.x; v[5] = (__bf16)f1.y; v[6] = (__bf16)f1.z; v[7] = (__bf16)f1.w;
    *(bf16x8*)(out + i) = v;
}

// ---------------- generic NT GEMM, m97 structure + XOR bank swizzle ----------------
// A [M,K] K-major, B [N,K] K-major, 128x128 tile, BK=32, 4 waves (2x2), each wave
// 64x64 as 4x4 of 16x16x32 MFMA. LDS tile [128][32] bf16; col-block b of row r
// stored at physical block b ^ ((r>>1)&3) -> spreads b128 reads over all 8
// 16B bank-groups (2-way max = free).
// FUSE=1: Out[idx] = silu(acc) * (float)A1[idx]  (A1 may alias Out: same-thread RMW)
template<int KD, int FUSE, typename OutT>
__global__ __launch_bounds__(256) void gemm_nt(
    const __bf16* __restrict__ A, const __bf16* __restrict__ B,
    const __bf16* __restrict__ A1, OutT* __restrict__ Out, const int N)
{
    __shared__ __bf16 As[128 * 32];
    __shared__ __bf16 Bs[128 * 32];

    const int tid  = threadIdx.x;
    const int lane = tid & 63;
    const int wave = tid >> 6;
    const int wm = wave >> 1, wn = wave & 1;
    const long m0 = (long)blockIdx.y * 128;
    const long n0 = (long)blockIdx.x * 128;

    // staging: wave w rows w*16..w*16+15 (pass p adds 64); lane l -> row +(l>>2),
    // physical col-block l&3 which receives global col-block (l&3)^f(row)
    const int  srow = wave * 16 + (lane >> 2);
    const int  f_st = (srow >> 1) & 3;
    const int  scol = ((lane & 3) ^ f_st) * 8;
    const __bf16* Ag = A + (m0 + srow) * (long)KD + scol;
    const __bf16* Bg = B + (n0 + srow) * (long)KD + scol;
    const int lds_base = wave * 16 * 32;  // elements; wave-uniform

    // compute-side fragment offsets: want global col-block j=lane>>4 of row
    // base_r(+16i); stored at physical block j ^ ((base_r>>1)&3) (i-invariant).
    const int base_ra = wm * 64 + (lane & 15);
    const int base_rb = wn * 64 + (lane & 15);
    const int f_rd = ((lane & 15) >> 1) & 3;   // (base_r>>1)&3, wm/wn*32 has &3==0
    const int ar = base_ra * 32 + ((lane >> 4) ^ f_rd) * 8;
    const int br = base_rb * 32 + ((lane >> 4) ^ f_rd) * 8;

    const f32x4 zero = {0.f, 0.f, 0.f, 0.f};
    f32x4 acc[4][4];
#pragma unroll
    for (int i = 0; i < 4; ++i)
#pragma unroll
        for (int j = 0; j < 4; ++j) acc[i][j] = zero;

    for (int k0 = 0; k0 < KD; k0 += 32) {
#pragma unroll
        for (int p = 0; p < 2; ++p) {
            async_lds16(Ag + (long)p * 64 * KD + k0, &As[lds_base + p * 64 * 32]);
            async_lds16(Bg + (long)p * 64 * KD + k0, &Bs[lds_base + p * 64 * 32]);
        }
        __syncthreads();
        bf16x8 af[4], bf[4];
#pragma unroll
        for (int i = 0; i < 4; ++i) {
            af[i] = *(const bf16x8*)(As + ar + i * 16 * 32);
            bf[i] = *(const bf16x8*)(Bs + br + i * 16 * 32);
        }
#pragma unroll
        for (int mi = 0; mi < 4; ++mi)
#pragma unroll
            for (int ni = 0; ni < 4; ++ni)
                acc[mi][ni] = __builtin_amdgcn_mfma_f32_16x16x32_bf16(af[mi], bf[ni], acc[mi][ni], 0, 0, 0);
        __syncthreads();
    }

    // epilogue: C/D layout col=lane&15, row=(lane>>4)*4+reg
    const long crow = m0 + wm * 64 + ((lane >> 4) * 4);
    const long ccol = n0 + wn * 64 + (lane & 15);
#pragma unroll
    for (int mi = 0; mi < 4; ++mi)
#pragma unroll
        for (int ni = 0; ni < 4; ++ni)
#pragma unroll
            for (int r = 0; r < 4; ++r) {
                const long idx = (crow + mi * 16 + r) * (long)N + (ccol + ni * 16);
                float a = acc[mi][ni][r];
                if (FUSE) {
                    float b = (float)A1[idx];
                    float sg = 1.0f / (1.0f + __expf(-a));
                    Out[idx] = (OutT)(a * sg * b);
                } else {
                    Out[idx] = (OutT)a;
                }
            }
}

extern "C" void kernel_launch(void* const* d_in, const int* in_sizes, int n_in,
                              void* d_out, int out_size, void* d_ws, size_t ws_size,
                              hipStream_t stream) {
    const float* x   = (const float*)d_in[0];
    const int*   w1c = (const int*)d_in[1];
    const float* w1s = (const float*)d_in[2];
    const int*   w2c = (const int*)d_in[3];
    const float* w2s = (const float*)d_in[4];
    const int*   w3c = (const int*)d_in[5];
    const float* w3s = (const float*)d_in[6];
    float* out = (float*)d_out;

    // workspace layout (~517 MiB): xb, w1b, w2b, w3b, a2/h (aliased in-place)
    char* ws = (char*)d_ws;
    __bf16* xb  = (__bf16*)ws;  ws += (size_t)T_DIM * D_DIM * 2;
    __bf16* w1b = (__bf16*)ws;  ws += (size_t)H_DIM * D_DIM * 2;
    __bf16* w2b = (__bf16*)ws;  ws += (size_t)H_DIM * D_DIM * 2;
    __bf16* w3b = (__bf16*)ws;  ws += (size_t)H_DIM * D_DIM * 2;
    __bf16* hb  = (__bf16*)ws;  // T*H bf16; holds a2, then h in-place

    const long nx = (long)T_DIM * D_DIM;   // 33,554,432
    const long nw = (long)H_DIM * D_DIM;   // 45,088,768

    cvt_f32_bf16<<<(int)(nx / (256 * 8)), 256, 0, stream>>>(x, xb, nx);
    dequant_nf4_kernel<<<(int)(nw / (256 * 8)), 256, 0, stream>>>(w1c, w1s, w1b, nw);
    dequant_nf4_kernel<<<(int)(nw / (256 * 8)), 256, 0, stream>>>(w2c, w2s, w2b, nw);
    dequant_nf4_kernel<<<(int)(nw / (256 * 8)), 256, 0, stream>>>(w3c, w3s, w3b, nw);

    // a2 = x @ w2^T
    gemm_nt<D_DIM, 0, __bf16><<<dim3(H_DIM / 128, T_DIM / 128), 256, 0, stream>>>(
        xb, w2b, nullptr, hb, H_DIM);
    // h = silu(x @ w1^T) * a2   (in-place over a2)
    gemm_nt<D_DIM, 1, __bf16><<<dim3(H_DIM / 128, T_DIM / 128), 256, 0, stream>>>(
        xb, w1b, hb, hb, H_DIM);
    // out = h @ w3^T
    gemm_nt<H_DIM, 0, float><<<dim3(D_DIM / 128, T_DIM / 128), 256, 0, stream>>>(
        hb, w3b, nullptr, out, D_DIM);
}

// Round 3
// 3280.852 us; speedup vs baseline: 1.4905x; 1.2146x over previous
//
#include <hip/hip_runtime.h>
#include <hip/hip_bf16.h>

// Problem dims (fixed by the reference)
#define T_DIM 8192
#define D_DIM 4096
#define H_DIM 11008

typedef __attribute__((ext_vector_type(8))) __bf16 bf16x8;
typedef __attribute__((ext_vector_type(4))) float f32x4;
typedef __attribute__((ext_vector_type(16))) float f32x16;

typedef __attribute__((address_space(1))) const void gvoid_t;
typedef __attribute__((address_space(3))) void lvoid_t;

__device__ __forceinline__ void async_lds16(const void* g, void* l) {
    // 16B per lane, LDS dest = wave-uniform base + lane*16
    __builtin_amdgcn_global_load_lds((gvoid_t*)g, (lvoid_t*)l, 16, 0, 0);
}

__device__ const float NF4_TAB[16] = {
    -1.0f, -0.6961928009986877f, -0.5250730514526367f, -0.39491748809814453f,
    -0.28444138169288635f, -0.18477343022823334f, -0.09105003625154495f, 0.0f,
    0.07958029955625534f, 0.16093020141124725f, 0.24611230194568634f,
    0.33791524171829224f, 0.44070982933044434f, 0.5626170039176941f,
    0.7229568362236023f, 1.0f};

// ---------------- dequant: int32 codes + per-64 scalers -> bf16 ----------------
__global__ void dequant_nf4_kernel(const int* __restrict__ codes,
                                   const float* __restrict__ scalers,
                                   __bf16* __restrict__ out, long n) {
    __shared__ float tbl[16];
    if (threadIdx.x < 16) tbl[threadIdx.x] = NF4_TAB[threadIdx.x];
    __syncthreads();
    long i = ((long)blockIdx.x * blockDim.x + threadIdx.x) * 8;
    if (i >= n) return;
    float s = scalers[i >> 6];
    const int4* cp = (const int4*)(codes + i);
    int4 c0 = cp[0], c1 = cp[1];
    bf16x8 v;
    v[0] = (__bf16)(tbl[c0.x] * s);
    v[1] = (__bf16)(tbl[c0.y] * s);
    v[2] = (__bf16)(tbl[c0.z] * s);
    v[3] = (__bf16)(tbl[c0.w] * s);
    v[4] = (__bf16)(tbl[c1.x] * s);
    v[5] = (__bf16)(tbl[c1.y] * s);
    v[6] = (__bf16)(tbl[c1.z] * s);
    v[7] = (__bf16)(tbl[c1.w] * s);
    *(bf16x8*)(out + i) = v;
}

// ---------------- x: fp32 -> bf16 ----------------
__global__ void cvt_f32_bf16(const float* __restrict__ x, __bf16* __restrict__ out, long n) {
    long i = ((long)blockIdx.x * blockDim.x + threadIdx.x) * 8;
    if (i >= n) return;
    const float4* xp = (const float4*)(x + i);
    float4 f0 = xp[0], f1 = xp[1];
    bf16x8 v;
    v[0] = (__bf16)f0.x; v[1] = (__bf16)f0.y; v[2] = (__bf16)f0.z; v[3] = (__bf16)f0.w;
    v[4] = (__bf16)f1.x; v[5] = (__bf16)f1.y; v[6] = (__bf16)f1.z; v[7] = (__bf16)f1.w;
    *(bf16x8*)(out + i) = v;
}

// ---------------- generic NT GEMM: 128x128 tile, BK=64, 32x32x16 MFMA ----------------
// A [M,K] K-major, B [N,K] K-major. 4 waves (2x2), each wave 64x64 as 2x2 of 32x32.
// LDS tile [128][64] bf16 (128 B rows = 8 x 16B col-blocks). Swizzle: global col-block
// g of row r stored at physical block g ^ (r&7) -> each 8 consecutive lanes of a
// ds_read_b128 hit 8 distinct 16B bank-groups (conflict-free). The swizzle is applied
// on the GLOBAL address side of global_load_lds (LDS dest stays base + lane*16).
// FUSE=1: Out[idx] = silu(acc) * (float)A1[idx]  (A1 may alias Out: same-thread RMW)
template<int KD, int FUSE, typename OutT>
__global__ __launch_bounds__(256) void gemm_nt(
    const __bf16* __restrict__ A, const __bf16* __restrict__ B,
    const __bf16* __restrict__ A1, OutT* __restrict__ Out, const int N)
{
    __shared__ __bf16 As[128 * 64];
    __shared__ __bf16 Bs[128 * 64];

    const int tid  = threadIdx.x;
    const int lane = tid & 63;
    const int wave = tid >> 6;
    const int wm = wave >> 1, wn = wave & 1;
    const long m0 = (long)blockIdx.y * 128;
    const long n0 = (long)blockIdx.x * 128;

    // staging: pass p covers tile-rows p*32 + (tid>>3); thread covers global col-block
    // (tid&7) ^ (row&7). Since p*32 is a multiple of 8, row&7 = (tid>>3)&7 (p-invariant).
    const int srow = tid >> 3;                       // 0..31
    const int scolblk = (tid & 7) ^ (srow & 7);      // swizzled global 16B-block
    const __bf16* Ag = A + (m0 + srow) * (long)KD + scolblk * 8;
    const __bf16* Bg = B + (n0 + srow) * (long)KD + scolblk * 8;

    // fragment read offsets (elements) in [128][64] LDS tile:
    // row r = w*64 + mt*32 + (lane&31); global block g = kk*2 + (lane>>5);
    // physical block = g ^ (r&7) = g ^ (lane&7)  (w*64, mt*32 are multiples of 8)
    const int arow0 = (wm * 64 + (lane & 31)) * 64;
    const int brow0 = (wn * 64 + (lane & 31)) * 64;
    const int fr = lane & 7;
    const int gh = lane >> 5;

    const f32x16 zero16 = {0.f,0.f,0.f,0.f,0.f,0.f,0.f,0.f,0.f,0.f,0.f,0.f,0.f,0.f,0.f,0.f};
    f32x16 acc[2][2];
#pragma unroll
    for (int i = 0; i < 2; ++i)
#pragma unroll
        for (int j = 0; j < 2; ++j) acc[i][j] = zero16;

    for (int k0 = 0; k0 < KD; k0 += 64) {
#pragma unroll
        for (int p = 0; p < 4; ++p) {
            async_lds16(Ag + (long)p * 32 * KD + k0, &As[(p * 32 + wave * 8) * 64]);
            async_lds16(Bg + (long)p * 32 * KD + k0, &Bs[(p * 32 + wave * 8) * 64]);
        }
        __syncthreads();
#pragma unroll
        for (int kk = 0; kk < 4; ++kk) {
            const int off = ((kk * 2 + gh) ^ fr) * 8;
            bf16x8 a0 = *(const bf16x8*)(As + arow0 + off);
            bf16x8 a1 = *(const bf16x8*)(As + arow0 + 32 * 64 + off);
            bf16x8 b0 = *(const bf16x8*)(Bs + brow0 + off);
            bf16x8 b1 = *(const bf16x8*)(Bs + brow0 + 32 * 64 + off);
            acc[0][0] = __builtin_amdgcn_mfma_f32_32x32x16_bf16(a0, b0, acc[0][0], 0, 0, 0);
            acc[0][1] = __builtin_amdgcn_mfma_f32_32x32x16_bf16(a0, b1, acc[0][1], 0, 0, 0);
            acc[1][0] = __builtin_amdgcn_mfma_f32_32x32x16_bf16(a1, b0, acc[1][0], 0, 0, 0);
            acc[1][1] = __builtin_amdgcn_mfma_f32_32x32x16_bf16(a1, b1, acc[1][1], 0, 0, 0);
        }
        __syncthreads();
    }

    // epilogue: 32x32 C/D layout col=lane&31, row=(reg&3)+8*(reg>>2)+4*(lane>>5)
    const int col = lane & 31;
    const int rbase = 4 * (lane >> 5);
#pragma unroll
    for (int mt = 0; mt < 2; ++mt)
#pragma unroll
        for (int nt = 0; nt < 2; ++nt)
#pragma unroll
            for (int reg = 0; reg < 16; ++reg) {
                const long row = m0 + wm * 64 + mt * 32 + (reg & 3) + 8 * (reg >> 2) + rbase;
                const long idx = row * (long)N + (n0 + wn * 64 + nt * 32 + col);
                float a = acc[mt][nt][reg];
                if (FUSE) {
                    float b = (float)A1[idx];
                    float sg = 1.0f / (1.0f + __expf(-a));
                    Out[idx] = (OutT)(a * sg * b);
                } else {
                    Out[idx] = (OutT)a;
                }
            }
}

extern "C" void kernel_launch(void* const* d_in, const int* in_sizes, int n_in,
                              void* d_out, int out_size, void* d_ws, size_t ws_size,
                              hipStream_t stream) {
    const float* x   = (const float*)d_in[0];
    const int*   w1c = (const int*)d_in[1];
    const float* w1s = (const float*)d_in[2];
    const int*   w2c = (const int*)d_in[3];
    const float* w2s = (const float*)d_in[4];
    const int*   w3c = (const int*)d_in[5];
    const float* w3s = (const float*)d_in[6];
    float* out = (float*)d_out;

    // workspace layout (~517 MiB): xb, w1b, w2b, w3b, a2/h (aliased in-place)
    char* ws = (char*)d_ws;
    __bf16* xb  = (__bf16*)ws;  ws += (size_t)T_DIM * D_DIM * 2;
    __bf16* w1b = (__bf16*)ws;  ws += (size_t)H_DIM * D_DIM * 2;
    __bf16* w2b = (__bf16*)ws;  ws += (size_t)H_DIM * D_DIM * 2;
    __bf16* w3b = (__bf16*)ws;  ws += (size_t)H_DIM * D_DIM * 2;
    __bf16* hb  = (__bf16*)ws;  // T*H bf16; holds a2, then h in-place

    const long nx = (long)T_DIM * D_DIM;   // 33,554,432
    const long nw = (long)H_DIM * D_DIM;   // 45,088,768

    cvt_f32_bf16<<<(int)(nx / (256 * 8)), 256, 0, stream>>>(x, xb, nx);
    dequant_nf4_kernel<<<(int)(nw / (256 * 8)), 256, 0, stream>>>(w1c, w1s, w1b, nw);
    dequant_nf4_kernel<<<(int)(nw / (256 * 8)), 256, 0, stream>>>(w2c, w2s, w2b, nw);
    dequant_nf4_kernel<<<(int)(nw / (256 * 8)), 256, 0, stream>>>(w3c, w3s, w3b, nw);

    // a2 = x @ w2^T
    gemm_nt<D_DIM, 0, __bf16><<<dim3(H_DIM / 128, T_DIM / 128), 256, 0, stream>>>(
        xb, w2b, nullptr, hb, H_DIM);
    // h = silu(x @ w1^T) * a2   (in-place over a2)
    gemm_nt<D_DIM, 1, __bf16><<<dim3(H_DIM / 128, T_DIM / 128), 256, 0, stream>>>(
        xb, w1b, hb, hb, H_DIM);
    // out = h @ w3^T
    gemm_nt<H_DIM, 0, float><<<dim3(D_DIM / 128, T_DIM / 128), 256, 0, stream>>>(
        hb, w3b, nullptr, out, D_DIM);
}